// Round 18
// baseline (3202.256 us; speedup 1.0000x reference)
//
#include <hip/hip_runtime.h>
#include <math.h>

#define BB 16
#define CC 128
#define LL 16000
#define KK 256
#define SS 3937
#define MM 4000
#define THRS 0.5f
#define STEP 0.1f   // float32(0.01/0.1) == 0.1f

// ---------------------------------------------------------------------------
// Strided conv1d (K=256, stride=4), fp32 register-tiled implicit GEMM.
// R14 VERBATIM (proven ~60us). Single fmaf chain per output, k ascending.
// [bit-path frozen] tx=s (coalesced epilogue), ty=c, W natural rows in LDS
// stride 68, double-buffered. x window in LDS.
// MODE 0: init. MODE 1: LCA update. MODE 2: final -> hardshrink to d_out.
// ---------------------------------------------------------------------------
template<int MODE>
__global__ __launch_bounds__(256, 2) void k_conv(
    const float* __restrict__ in0,     // x (MODE 0) or recon (MODE 1/2)
    const float* __restrict__ W,       // [C][K] natural
    float* __restrict__ drive,
    float* __restrict__ u)
{
    __shared__ __align__(16) float sW[2][128 * 68];  // 2 x 34.8 KB
    __shared__ __align__(16) float sX[768];
    __shared__ int sFlag;

    const int tid = threadIdx.x;
    const int tx = tid & 15;          // s-minor
    const int ty = tid >> 4;          // c-minor
    const int s0 = blockIdx.x * 128;
    const int b  = blockIdx.y;

    const int sc = tid >> 1;
    const int sg = (tid & 1) * 8;
    const float4* W4 = (const float4*)W;

    if (tid == 0) sFlag = 0;
    __syncthreads();

    bool nz = false;
    #pragma unroll
    for (int h = 0; h < 3; ++h) {
        int t = tid + 256 * h;
        int l = 4 * s0 + t;
        float v = (l < LL) ? in0[b * LL + l] : 0.f;
        sX[t] = v;
        nz |= (v != 0.f);
    }
    if (MODE != 0) { if (nz) atomicOr(&sFlag, 1); }
    __syncthreads();

    float acc[8][8];
    #pragma unroll
    for (int i = 0; i < 8; ++i)
        #pragma unroll
        for (int j = 0; j < 8; ++j) acc[i][j] = 0.f;

    const bool doit = (MODE == 0) || (sFlag != 0);   // block-uniform

    if (doit) {
        {
            float4* dst = (float4*)sW[0];
            #pragma unroll
            for (int w = 0; w < 8; ++w)
                dst[sc * 17 + sg + w] = W4[sc * 64 + sg + w];
        }
        __syncthreads();

        for (int kc = 0; kc < 4; ++kc) {         // k chunks ascending
            float4 pre[8];
            if (kc < 3) {
                #pragma unroll
                for (int w = 0; w < 8; ++w)
                    pre[w] = W4[sc * 64 + (kc + 1) * 16 + sg + w];
            }

            const float* wbuf = sW[kc & 1];
            const int xoff = 64 * kc;

            for (int kk4 = 0; kk4 < 16; ++kk4) {          // k ascending
                float4 xq[8];
                #pragma unroll
                for (int j = 0; j < 8; ++j)
                    xq[j] = *(const float4*)&sX[4 * (tx + 16 * j) + xoff + 4 * kk4];
                float4 w4[8];
                #pragma unroll
                for (int i = 0; i < 8; ++i)
                    w4[i] = *(const float4*)&wbuf[(ty + 16 * i) * 68 + 4 * kk4];
                #pragma unroll
                for (int dk = 0; dk < 4; ++dk) {
                    #pragma unroll
                    for (int i = 0; i < 8; ++i) {
                        float wv = (&w4[i].x)[dk];
                        #pragma unroll
                        for (int j = 0; j < 8; ++j)
                            acc[i][j] = fmaf(wv, (&xq[j].x)[dk], acc[i][j]);
                    }
                }
            }

            if (kc < 3) {
                float4* dst = (float4*)sW[(kc + 1) & 1];
                #pragma unroll
                for (int w = 0; w < 8; ++w)
                    dst[sc * 17 + sg + w] = pre[w];
            }
            __syncthreads();
        }
    }

    // epilogue: locked fp32 elementwise chain; s-contiguous stores
    #pragma unroll
    for (int j = 0; j < 8; ++j) {
        int s = s0 + tx + 16 * j;
        if (s < SS) {
            #pragma unroll
            for (int i = 0; i < 8; ++i) {
                int c = ty + 16 * i;
                size_t idx = (size_t)(b * CC + c) * SS + s;
                if (MODE == 0) {
                    float d = acc[i][j];
                    drive[idx] = d;
                    u[idx] = __fmul_rn(STEP, d);   // u1 = 0 + 0.1f*drive
                } else {
                    float uo = u[idx];
                    float dr = drive[idx];
                    float a  = (fabsf(uo) > THRS) ? uo : 0.f;
                    float t1 = __fsub_rn(dr, uo);
                    float t2 = __fsub_rn(t1, acc[i][j]);
                    float t3 = __fadd_rn(t2, a);
                    float t4 = __fmul_rn(STEP, t3);
                    float un = __fadd_rn(uo, t4);
                    if (MODE == 1) u[idx] = un;
                    else           u[idx] = (fabsf(un) > THRS) ? un : 0.f;  // final
                }
            }
        }
    }
}

// ---------------------------------------------------------------------------
// Inner-loop asm macros for k_recon: 12-deep pipelined ds_read_b32 stream,
// readlanes one q ahead (>=4-instr SGPR-hazard distance), fmaf chain in the
// frozen order. lgkmcnt carries ONLY these ds_reads (enters/exits at 0).
//   QS: steady-state step (issues the q+12 read).  QT: tail (no issue).
// ---------------------------------------------------------------------------
#define QS(WC, JN, SL, OFF, C0, C1, C2, C3, N0, N1, N2, N3) \
    "s_waitcnt lgkmcnt(" #WC ")\n\t" \
    "v_readlane_b32 %[" #N0 "], %[wx], " #JN "\n\t" \
    "v_readlane_b32 %[" #N1 "], %[wy], " #JN "\n\t" \
    "v_readlane_b32 %[" #N2 "], %[wz], " #JN "\n\t" \
    "v_readlane_b32 %[" #N3 "], %[ww], " #JN "\n\t" \
    "v_fma_f32 %[a0], %[" #SL "], %[" #C0 "], %[a0]\n\t" \
    "v_fma_f32 %[a1], %[" #SL "], %[" #C1 "], %[a1]\n\t" \
    "v_fma_f32 %[a2], %[" #SL "], %[" #C2 "], %[a2]\n\t" \
    "v_fma_f32 %[a3], %[" #SL "], %[" #C3 "], %[a3]\n\t" \
    "ds_read_b32 %[" #SL "], %[ad] offset:" #OFF "\n\t"

#define QT(WC, JN, SL, C0, C1, C2, C3, N0, N1, N2, N3) \
    "s_waitcnt lgkmcnt(" #WC ")\n\t" \
    "v_readlane_b32 %[" #N0 "], %[wx], " #JN "\n\t" \
    "v_readlane_b32 %[" #N1 "], %[wy], " #JN "\n\t" \
    "v_readlane_b32 %[" #N2 "], %[wz], " #JN "\n\t" \
    "v_readlane_b32 %[" #N3 "], %[ww], " #JN "\n\t" \
    "v_fma_f32 %[a0], %[" #SL "], %[" #C0 "], %[a0]\n\t" \
    "v_fma_f32 %[a1], %[" #SL "], %[" #C1 "], %[a1]\n\t" \
    "v_fma_f32 %[a2], %[" #SL "], %[" #C2 "], %[a2]\n\t" \
    "v_fma_f32 %[a3], %[" #SL "], %[" #C3 "], %[a3]\n\t"

// ---------------------------------------------------------------------------
// Transpose-conv (recon). Chain [bit-path frozen] identical to R5-R17:
//   recon[b][4m+r]: for c = 0..127 asc (4 stages x 32), q = 0..63 asc:
//       acc_r = fmaf(a[b][c][m-63+q], W[c][4*(63-q)+r], acc_r)
// R18: inner 64-q loop in inline asm — 12 ds_read_b32 in flight with exact
// lgkmcnt(11) steady-state waits (in-order DS returns), readlanes pipelined
// one q ahead. Same instruction MIX as R9 (compiler version measured 196us
// at VALUBusy 42%); this controls the SCHEDULE the compiler wouldn't.
// ---------------------------------------------------------------------------
__global__ __launch_bounds__(256, 2) void k_recon(
    const float* __restrict__ u,
    const float* __restrict__ W,       // [C][K] natural layout
    float* __restrict__ recon)         // [B][LL]
{
    __shared__ __align__(16) float sA[32 * 320];   // 40.96 KB (stride 320)
    __shared__ int sFlag;

    const int tid = threadIdx.x;      // = m_local in [0,256)
    const int lane = tid & 63;
    const int m0 = blockIdx.x * 256;
    const int b  = blockIdx.y;
    const int m  = m0 + tid;

    if (tid == 0) sFlag = 0;
    __syncthreads();

    float acc0 = 0.f, acc1 = 0.f, acc2 = 0.f, acc3 = 0.f;

    for (int cs = 0; cs < 4; ++cs) {            // 32-channel stages, c ascending
        const int c0 = cs * 32;
        bool nz = false;
        for (int cl = 0; cl < 32; ++cl) {
            const float* urow = u + (size_t)(b * CC + c0 + cl) * SS + (m0 - 63);
            #pragma unroll
            for (int h = 0; h < 2; ++h) {
                int col = tid + 256 * h;
                if (col < 319) {
                    int mm = m0 - 63 + col;
                    float v = 0.f;
                    if (mm >= 0 && mm < SS) {
                        float uu = urow[col];
                        v = (fabsf(uu) > THRS) ? uu : 0.f;
                    }
                    sA[cl * 320 + col] = v;
                    nz |= (v != 0.f);
                }
            }
        }
        if (nz) atomicOr(&sFlag, 1);
        __syncthreads();                        // staging + flags complete
        const int f = sFlag;                    // block-uniform read
        __syncthreads();                        // all threads have read f
        if (tid == 0) sFlag = 0;                // reset (ordered by loop-end barrier)

        if (f) {
            for (int cl = 0; cl < 32; ++cl) {   // c ascending
                unsigned ad = (unsigned)(size_t)(sA + cl * 320 + tid);
                float4 wv = ((const float4*)(W + (size_t)(c0 + cl) * KK))[lane];
                float z0, z1, z2, z3, z4, z5, z6, z7, z8, z9, z10, z11;
                float t0, t1, t2, t3, t4, t5, t6, t7;

                asm volatile(
                    // prologue: 12 reads in flight (q = 0..11)
                    "ds_read_b32 %[z0],  %[ad] offset:0\n\t"
                    "ds_read_b32 %[z1],  %[ad] offset:4\n\t"
                    "ds_read_b32 %[z2],  %[ad] offset:8\n\t"
                    "ds_read_b32 %[z3],  %[ad] offset:12\n\t"
                    "ds_read_b32 %[z4],  %[ad] offset:16\n\t"
                    "ds_read_b32 %[z5],  %[ad] offset:20\n\t"
                    "ds_read_b32 %[z6],  %[ad] offset:24\n\t"
                    "ds_read_b32 %[z7],  %[ad] offset:28\n\t"
                    "ds_read_b32 %[z8],  %[ad] offset:32\n\t"
                    "ds_read_b32 %[z9],  %[ad] offset:36\n\t"
                    "ds_read_b32 %[z10], %[ad] offset:40\n\t"
                    "ds_read_b32 %[z11], %[ad] offset:44\n\t"
                    // preload w scalars for q=0 (j=63)
                    "v_readlane_b32 %[t0], %[wx], 63\n\t"
                    "v_readlane_b32 %[t1], %[wy], 63\n\t"
                    "v_readlane_b32 %[t2], %[wz], 63\n\t"
                    "v_readlane_b32 %[t3], %[ww], 63\n\t"
                    QS(11, 62, z0,  48,  t0,t1,t2,t3, t4,t5,t6,t7)   // q=0
                    QS(11, 61, z1,  52,  t4,t5,t6,t7, t0,t1,t2,t3)   // q=1
                    QS(11, 60, z2,  56,  t0,t1,t2,t3, t4,t5,t6,t7)   // q=2
                    QS(11, 59, z3,  60,  t4,t5,t6,t7, t0,t1,t2,t3)   // q=3
                    QS(11, 58, z4,  64,  t0,t1,t2,t3, t4,t5,t6,t7)   // q=4
                    QS(11, 57, z5,  68,  t4,t5,t6,t7, t0,t1,t2,t3)   // q=5
                    QS(11, 56, z6,  72,  t0,t1,t2,t3, t4,t5,t6,t7)   // q=6
                    QS(11, 55, z7,  76,  t4,t5,t6,t7, t0,t1,t2,t3)   // q=7
                    QS(11, 54, z8,  80,  t0,t1,t2,t3, t4,t5,t6,t7)   // q=8
                    QS(11, 53, z9,  84,  t4,t5,t6,t7, t0,t1,t2,t3)   // q=9
                    QS(11, 52, z10, 88,  t0,t1,t2,t3, t4,t5,t6,t7)   // q=10
                    QS(11, 51, z11, 92,  t4,t5,t6,t7, t0,t1,t2,t3)   // q=11
                    QS(11, 50, z0,  96,  t0,t1,t2,t3, t4,t5,t6,t7)   // q=12
                    QS(11, 49, z1,  100, t4,t5,t6,t7, t0,t1,t2,t3)   // q=13
                    QS(11, 48, z2,  104, t0,t1,t2,t3, t4,t5,t6,t7)   // q=14
                    QS(11, 47, z3,  108, t4,t5,t6,t7, t0,t1,t2,t3)   // q=15
                    QS(11, 46, z4,  112, t0,t1,t2,t3, t4,t5,t6,t7)   // q=16
                    QS(11, 45, z5,  116, t4,t5,t6,t7, t0,t1,t2,t3)   // q=17
                    QS(11, 44, z6,  120, t0,t1,t2,t3, t4,t5,t6,t7)   // q=18
                    QS(11, 43, z7,  124, t4,t5,t6,t7, t0,t1,t2,t3)   // q=19
                    QS(11, 42, z8,  128, t0,t1,t2,t3, t4,t5,t6,t7)   // q=20
                    QS(11, 41, z9,  132, t4,t5,t6,t7, t0,t1,t2,t3)   // q=21
                    QS(11, 40, z10, 136, t0,t1,t2,t3, t4,t5,t6,t7)   // q=22
                    QS(11, 39, z11, 140, t4,t5,t6,t7, t0,t1,t2,t3)   // q=23
                    QS(11, 38, z0,  144, t0,t1,t2,t3, t4,t5,t6,t7)   // q=24
                    QS(11, 37, z1,  148, t4,t5,t6,t7, t0,t1,t2,t3)   // q=25
                    QS(11, 36, z2,  152, t0,t1,t2,t3, t4,t5,t6,t7)   // q=26
                    QS(11, 35, z3,  156, t4,t5,t6,t7, t0,t1,t2,t3)   // q=27
                    QS(11, 34, z4,  160, t0,t1,t2,t3, t4,t5,t6,t7)   // q=28
                    QS(11, 33, z5,  164, t4,t5,t6,t7, t0,t1,t2,t3)   // q=29
                    QS(11, 32, z6,  168, t0,t1,t2,t3, t4,t5,t6,t7)   // q=30
                    QS(11, 31, z7,  172, t4,t5,t6,t7, t0,t1,t2,t3)   // q=31
                    QS(11, 30, z8,  176, t0,t1,t2,t3, t4,t5,t6,t7)   // q=32
                    QS(11, 29, z9,  180, t4,t5,t6,t7, t0,t1,t2,t3)   // q=33
                    QS(11, 28, z10, 184, t0,t1,t2,t3, t4,t5,t6,t7)   // q=34
                    QS(11, 27, z11, 188, t4,t5,t6,t7, t0,t1,t2,t3)   // q=35
                    QS(11, 26, z0,  192, t0,t1,t2,t3, t4,t5,t6,t7)   // q=36
                    QS(11, 25, z1,  196, t4,t5,t6,t7, t0,t1,t2,t3)   // q=37
                    QS(11, 24, z2,  200, t0,t1,t2,t3, t4,t5,t6,t7)   // q=38
                    QS(11, 23, z3,  204, t4,t5,t6,t7, t0,t1,t2,t3)   // q=39
                    QS(11, 22, z4,  208, t0,t1,t2,t3, t4,t5,t6,t7)   // q=40
                    QS(11, 21, z5,  212, t4,t5,t6,t7, t0,t1,t2,t3)   // q=41
                    QS(11, 20, z6,  216, t0,t1,t2,t3, t4,t5,t6,t7)   // q=42
                    QS(11, 19, z7,  220, t4,t5,t6,t7, t0,t1,t2,t3)   // q=43
                    QS(11, 18, z8,  224, t0,t1,t2,t3, t4,t5,t6,t7)   // q=44
                    QS(11, 17, z9,  228, t4,t5,t6,t7, t0,t1,t2,t3)   // q=45
                    QS(11, 16, z10, 232, t0,t1,t2,t3, t4,t5,t6,t7)   // q=46
                    QS(11, 15, z11, 236, t4,t5,t6,t7, t0,t1,t2,t3)   // q=47
                    QS(11, 14, z0,  240, t0,t1,t2,t3, t4,t5,t6,t7)   // q=48
                    QS(11, 13, z1,  244, t4,t5,t6,t7, t0,t1,t2,t3)   // q=49
                    QS(11, 12, z2,  248, t0,t1,t2,t3, t4,t5,t6,t7)   // q=50
                    QS(11, 11, z3,  252, t4,t5,t6,t7, t0,t1,t2,t3)   // q=51
                    QT(11, 10, z4,       t0,t1,t2,t3, t4,t5,t6,t7)   // q=52
                    QT(10, 9,  z5,       t4,t5,t6,t7, t0,t1,t2,t3)   // q=53
                    QT(9,  8,  z6,       t0,t1,t2,t3, t4,t5,t6,t7)   // q=54
                    QT(8,  7,  z7,       t4,t5,t6,t7, t0,t1,t2,t3)   // q=55
                    QT(7,  6,  z8,       t0,t1,t2,t3, t4,t5,t6,t7)   // q=56
                    QT(6,  5,  z9,       t4,t5,t6,t7, t0,t1,t2,t3)   // q=57
                    QT(5,  4,  z10,      t0,t1,t2,t3, t4,t5,t6,t7)   // q=58
                    QT(4,  3,  z11,      t4,t5,t6,t7, t0,t1,t2,t3)   // q=59
                    QT(3,  2,  z0,       t0,t1,t2,t3, t4,t5,t6,t7)   // q=60
                    QT(2,  1,  z1,       t4,t5,t6,t7, t0,t1,t2,t3)   // q=61
                    QT(1,  0,  z2,       t0,t1,t2,t3, t4,t5,t6,t7)   // q=62
                    QT(0,  0,  z3,       t4,t5,t6,t7, t0,t1,t2,t3)   // q=63
                    : [a0]"+v"(acc0), [a1]"+v"(acc1), [a2]"+v"(acc2), [a3]"+v"(acc3),
                      [z0]"=&v"(z0), [z1]"=&v"(z1), [z2]"=&v"(z2), [z3]"=&v"(z3),
                      [z4]"=&v"(z4), [z5]"=&v"(z5), [z6]"=&v"(z6), [z7]"=&v"(z7),
                      [z8]"=&v"(z8), [z9]"=&v"(z9), [z10]"=&v"(z10), [z11]"=&v"(z11),
                      [t0]"=&s"(t0), [t1]"=&s"(t1), [t2]"=&s"(t2), [t3]"=&s"(t3),
                      [t4]"=&s"(t4), [t5]"=&s"(t5), [t6]"=&s"(t6), [t7]"=&s"(t7)
                    : [ad]"v"(ad), [wx]"v"(wv.x), [wy]"v"(wv.y),
                      [wz]"v"(wv.z), [ww]"v"(wv.w)
                    : "memory");
            }
        }
        __syncthreads();   // sA reads done + sFlag reset visible before next stage
    }

    if (m < MM) {
        float4* o = (float4*)(recon + (size_t)b * LL + 4 * m);
        *o = make_float4(acc0, acc1, acc2, acc3);
    }
}

extern "C" void kernel_launch(void* const* d_in, const int* in_sizes, int n_in,
                              void* d_out, int out_size, void* d_ws, size_t ws_size,
                              hipStream_t stream) {
    const float* x = (const float*)d_in[0];   // [16][1][16000]
    const float* W = (const float*)d_in[1];   // [128][1][256]
    float* u = (float*)d_out;                 // u lives in d_out (fp32)

    float* ws    = (float*)d_ws;              // ~33.3 MB used
    float* drive = ws;                                    // 8062976
    float* recon = drive + (size_t)BB * CC * SS;          // 256000

    dim3 gConv(31, 16);   // ceil(3937/128) x B
    k_conv<0><<<gConv, 256, 0, stream>>>(x, W, drive, u);   // drive + u1

    for (int it = 0; it < 9; ++it) {   // iterations 2..10
        k_recon<<<dim3(16, 16), 256, 0, stream>>>(u, W, recon);
        if (it < 8)
            k_conv<1><<<gConv, 256, 0, stream>>>(recon, W, drive, u);
        else
            k_conv<2><<<gConv, 256, 0, stream>>>(recon, W, drive, u);  // final -> d_out
    }
}